// Round 2
// baseline (268.145 us; speedup 1.0000x reference)
//
#include <hip/hip_runtime.h>
#include <math.h>

#define N_NODES 50000
#define N_EDGES 800000
#define BATCHES 128
#define DIM 64
#define HID 128
#define NCLS 2
#define EPSV 1e-5f
#define MAXD 64                                   // padded CSR row stride

#define NPART 8
#define PART_SZ ((N_NODES + NPART - 1) / NPART)   // 6250
#define EPB 2048
#define NCHK_E ((N_EDGES + EPB - 1) / EPB)        // 391
#define NBLK 391                                  // mega grid; 2 tiles/block -> 782 tiles

typedef __attribute__((ext_vector_type(8))) short bf16x8;
typedef __attribute__((ext_vector_type(4))) float f32x4;

// ---- fp32 -> bf16 hi/lo split helpers ----
__device__ __forceinline__ unsigned short f2bf(float f){
  unsigned u = __float_as_uint(f);
  u += 0x7FFFu + ((u >> 16) & 1u);     // RNE
  return (unsigned short)(u >> 16);
}
__device__ __forceinline__ float bf2f(unsigned short h){
  return __uint_as_float(((unsigned)h) << 16);
}
__device__ __forceinline__ void split2(float f, unsigned short& hi, unsigned short& lo){
  hi = f2bf(f);
  lo = f2bf(f - bf2f(hi));
}
__device__ __forceinline__ uint4 pack8(const unsigned short* s){
  uint4 u;
  u.x = (unsigned)s[0] | ((unsigned)s[1] << 16);
  u.y = (unsigned)s[2] | ((unsigned)s[3] << 16);
  u.z = (unsigned)s[4] | ((unsigned)s[5] << 16);
  u.w = (unsigned)s[6] | ((unsigned)s[7] << 16);
  return u;
}

// ---- agent-scope (L3-coherent) scalar access: cross-XCD safe ----
__device__ __forceinline__ void gstore(float* p, float v){
  __hip_atomic_store(p, v, __ATOMIC_RELAXED, __HIP_MEMORY_SCOPE_AGENT);
}
__device__ __forceinline__ float gload(const float* p){
  return __hip_atomic_load(p, __ATOMIC_RELAXED, __HIP_MEMORY_SCOPE_AGENT);
}

// ---- software grid barrier (all NBLK blocks co-resident by construction:
//      LDS 53.8KB -> 2 blk/CU, VGPR<=256 via launch_bounds -> 512 slots >= 391)
__device__ __forceinline__ void gbar(unsigned* c){
  __syncthreads();                       // all block mem ops drained (vmcnt 0)
  if (threadIdx.x == 0){
    __threadfence();                     // release: L2 writeback
    atomicAdd(c, 1u);
    while (atomicAdd(c, 0u) < (unsigned)NBLK) __builtin_amdgcn_s_sleep(16);
    __threadfence();                     // acquire: L1/L2 invalidate
  }
  __syncthreads();
}

// ---- K1: partitioned fixed-slot scatter -> ushort CSR + cnt ----
__global__ void k_scatter(const int* __restrict__ ei, int* __restrict__ cnt,
                          unsigned short* __restrict__ csr){
  const int p = blockIdx.x & (NPART-1);
  const int c = blockIdx.x >> 3;
  const int lo = p * PART_SZ;
  const int hi = lo + PART_SZ;
  const int e0 = c * EPB;
  const int e1 = (e0 + EPB < N_EDGES) ? e0 + EPB : N_EDGES;
  for (int i = e0 + threadIdx.x; i < e1; i += 256){
    int d = ei[N_EDGES + i];
    if (d >= lo && d < hi){
      int s = ei[i];
      int pos = atomicAdd(&cnt[d], 1);
      csr[(size_t)d*MAXD + pos] = (unsigned short)s;
    }
  }
}

// ---- K2: per-node gather mean (standalone, max wave parallelism). ----
__global__ void k_mean(const float* __restrict__ x,
                       const unsigned short* __restrict__ csr,
                       const int* __restrict__ cnt, float* __restrict__ meanb){
  const int node = (blockIdx.x*256 + threadIdx.x) >> 6;
  const int lane = threadIdx.x & 63;
  const int g = lane >> 4, f = lane & 15;
  const int dg = cnt[node];
  const size_t start = (size_t)node * MAXD;
  float4 acc = make_float4(0.f,0.f,0.f,0.f);
  int e = (lane < dg) ? (int)csr[start + lane] : 0;
  int i = 0;
  for (; i + 16 <= dg; i += 16){
    int s0 = __shfl(e, i +      g, 64);
    int s1 = __shfl(e, i + 4  + g, 64);
    int s2 = __shfl(e, i + 8  + g, 64);
    int s3 = __shfl(e, i + 12 + g, 64);
    float4 v0 = *(const float4*)&x[(size_t)s0*DIM + f*4];
    float4 v1 = *(const float4*)&x[(size_t)s1*DIM + f*4];
    float4 v2 = *(const float4*)&x[(size_t)s2*DIM + f*4];
    float4 v3 = *(const float4*)&x[(size_t)s3*DIM + f*4];
    acc.x += v0.x + v1.x + v2.x + v3.x;
    acc.y += v0.y + v1.y + v2.y + v3.y;
    acc.z += v0.z + v1.z + v2.z + v3.z;
    acc.w += v0.w + v1.w + v2.w + v3.w;
  }
  for (; i < dg; i += 4){
    int idx = i + g;
    int srcl = (idx < dg) ? idx : (dg - 1);   // clamp: valid-lane shfl
    int s = __shfl(e, srcl, 64);
    if (idx < dg){
      float4 v = *(const float4*)&x[(size_t)s*DIM + f*4];
      acc.x += v.x; acc.y += v.y; acc.z += v.z; acc.w += v.w;
    }
  }
  acc.x += __shfl_xor(acc.x, 16, 64); acc.x += __shfl_xor(acc.x, 32, 64);
  acc.y += __shfl_xor(acc.y, 16, 64); acc.y += __shfl_xor(acc.y, 32, 64);
  acc.z += __shfl_xor(acc.z, 16, 64); acc.z += __shfl_xor(acc.z, 32, 64);
  acc.w += __shfl_xor(acc.w, 16, 64); acc.w += __shfl_xor(acc.w, 32, 64);
  if (g == 0){
    float inv = 1.f / fmaxf((float)dg, 1.f);
    float4 r = make_float4(acc.x*inv, acc.y*inv, acc.z*inv, acc.w*inv);
    *(float4*)&meanb[(size_t)node*DIM + f*4] = r;
  }
}

// helper: stage TWO 64x64 weights (k<64 -> W0, k>=64 -> W1) transposed as
// bf16 hi/lo into [64][136] rows (resident across the whole phase)
__device__ __forceinline__ void stage_w128(short* sBh, short* sBl,
                                           const float* __restrict__ W0,
                                           const float* __restrict__ W1,
                                           int w, int lane){
  const int k0 = 32 * w;
  #pragma unroll
  for (int kc = 0; kc < 4; ++kc){
    unsigned short h[8], l[8];
    #pragma unroll
    for (int i = 0; i < 8; ++i){
      int k = k0 + 8*kc + i;
      float v = (k < 64) ? W0[k*DIM + lane] : W1[(k-64)*DIM + lane];
      split2(v, h[i], l[i]);
    }
    *(uint4*)&sBh[lane*136 + k0 + 8*kc] = pack8(h);
    *(uint4*)&sBl[lane*136 + k0 + 8*kc] = pack8(l);
  }
}

// 64-wide-K split-bf16 GEMM: ACC += A(64x64 from sA) @ B(64n x 64k at col
// offset KB0 of resident sB)^T
#define GEMM64B(SA, SB, ACC, KB0) do { \
  _Pragma("unroll") \
  for (int kt2 = 0; kt2 < 2; ++kt2){ \
    const int ka = kt2*32 + koff; \
    bf16x8 ah = *(const bf16x8*)&SA[0][mrow][ka]; \
    bf16x8 al = *(const bf16x8*)&SA[1][mrow][ka]; \
    _Pragma("unroll") \
    for (int nt = 0; nt < 4; ++nt){ \
      const int nr = nt*16 + jc; \
      bf16x8 bh = *(const bf16x8*)&SB[0][nr][(KB0) + ka]; \
      bf16x8 bo = *(const bf16x8*)&SB[1][nr][(KB0) + ka]; \
      ACC[nt] = __builtin_amdgcn_mfma_f32_16x16x32_bf16(ah, bh, ACC[nt], 0,0,0); \
      ACC[nt] = __builtin_amdgcn_mfma_f32_16x16x32_bf16(al, bh, ACC[nt], 0,0,0); \
      ACC[nt] = __builtin_amdgcn_mfma_f32_16x16x32_bf16(ah, bo, ACC[nt], 0,0,0); \
    } \
  } \
} while(0)

// stage 64 node-rows of a (N,DIM) f32 matrix into sA as bf16 hi/lo
#define STAGE_A(SRC, BASE) do { \
  const int row_  = tid >> 2; \
  const int kq_   = (tid & 3) * 16; \
  const int node_ = (BASE) + row_; \
  _Pragma("unroll") \
  for (int cc = 0; cc < 4; ++cc){ \
    float4 v = make_float4(0.f,0.f,0.f,0.f); \
    if (node_ < N_NODES) v = *(const float4*)&SRC[(size_t)node_*DIM + kq_ + 4*cc]; \
    unsigned short h_[4], l_[4]; \
    split2(v.x,h_[0],l_[0]); split2(v.y,h_[1],l_[1]); \
    split2(v.z,h_[2],l_[2]); split2(v.w,h_[3],l_[3]); \
    uint2 ph_, pl_; \
    ph_.x = (unsigned)h_[0] | ((unsigned)h_[1]<<16); \
    ph_.y = (unsigned)h_[2] | ((unsigned)h_[3]<<16); \
    pl_.x = (unsigned)l_[0] | ((unsigned)l_[1]<<16); \
    pl_.y = (unsigned)l_[2] | ((unsigned)l_[3]<<16); \
    *(uint2*)&sA[0][row_][kq_ + 4*cc] = ph_; \
    *(uint2*)&sA[1][row_][kq_ + 4*cc] = pl_; \
  } \
} while(0)

// phase-1 per-tile: acc = [mean|x] @ [Wl;Wr]  (sB resident, two A-stages)
#define LIN1_TILE(BASE, ACC) do { \
  STAGE_A(meanb, BASE); \
  __syncthreads(); \
  GEMM64B(sA, sB, ACC, 0); \
  __syncthreads(); \
  STAGE_A(x, BASE); \
  __syncthreads(); \
  GEMM64B(sA, sB, ACC, 64); \
  __syncthreads(); \
} while(0)

// phase-1 epilogue per-tile: +bl, retain hpre, accumulate stats partials
#define EPI1(BASE, ACC) do { \
  _Pragma("unroll") \
  for (int nt = 0; nt < 4; ++nt){ \
    _Pragma("unroll") \
    for (int r = 0; r < 4; ++r){ \
      const int node_ = (BASE) + r0 + r; \
      float v_ = ACC[nt][r] + blv[nt]; \
      ACC[nt][r] = v_; \
      if (node_ < N_NODES){ s1v[nt] += v_; s2v[nt] += v_*v_; } \
    } \
  } \
} while(0)

// phase-3 per-tile: h2 = BN(hpre)+x@Wres+bres ; gate ; fused attn pooling.
// ACC holds hpre on entry, h2 on exit. sB holds [Wres|gW1] resident.
#define LIN2_TILE(BASE, ACC) do { \
  if (tid < 64){ \
    int nn_ = (BASE) + tid; \
    sb[tid] = batch[(nn_ < N_NODES) ? nn_ : (N_NODES-1)]; \
  } \
  STAGE_A(x, BASE); \
  __syncthreads(); \
  if (w == 0){ \
    bool fl_ = (lane > 0) && (sb[lane] != sb[lane-1]); \
    unsigned long long mm_ = __ballot(fl_); \
    if (lane == 0) runmask = mm_; \
  } \
  f32x4 acc2_[4] = {}; \
  GEMM64B(sA, sB, acc2_, 0); \
  _Pragma("unroll") \
  for (int nt = 0; nt < 4; ++nt){ \
    const int col_ = nt*16 + jc; \
    _Pragma("unroll") \
    for (int r = 0; r < 4; ++r){ \
      float v_ = (ACC[nt][r] - muv[nt])*invv[nt]*gav[nt] + bev[nt] \
               + brv[nt] + acc2_[nt][r]; \
      ACC[nt][r] = v_; \
      unsigned short hh_, ll_; \
      split2(v_, hh_, ll_); \
      sA[0][r0 + r][col_] = (short)hh_; \
      sA[1][r0 + r][col_] = (short)ll_; \
    } \
  } \
  __syncthreads(); \
  f32x4 acc3_[4] = {}; \
  GEMM64B(sA, sB, acc3_, 64); \
  float p_[4] = {0.f,0.f,0.f,0.f}; \
  _Pragma("unroll") \
  for (int nt = 0; nt < 4; ++nt){ \
    _Pragma("unroll") \
    for (int r = 0; r < 4; ++r) \
      p_[r] += fmaxf(acc3_[nt][r] + g1v[nt], 0.f) * w2v[nt]; \
  } \
  float ev_[4]; \
  _Pragma("unroll") \
  for (int r = 0; r < 4; ++r){ \
    float t_ = p_[r]; \
    t_ += __shfl_xor(t_, 1, 64); t_ += __shfl_xor(t_, 2, 64); \
    t_ += __shfl_xor(t_, 4, 64); t_ += __shfl_xor(t_, 8, 64); \
    const int node_ = (BASE) + r0 + r; \
    ev_[r] = (node_ < N_NODES) ? expf(t_ + gb2v) : 0.f; \
  } \
  float* sredp_ = (float*)&sA[0][0][0]; \
  float* szl_   = sredp_ + 16*64; \
  __syncthreads(); \
  const unsigned long long m_ = runmask; \
  int rstart_ = 0; \
  while (rstart_ < 64){ \
    const int bseg_ = sb[rstart_]; \
    unsigned long long rest_ = (rstart_ >= 63) ? 0ull : (m_ >> (rstart_+1)); \
    const int rend_ = rest_ ? (rstart_ + 1 + __builtin_ctzll(rest_)) : 64; \
    float pacc_[4] = {0.f,0.f,0.f,0.f}; \
    float zacc_ = 0.f; \
    _Pragma("unroll") \
    for (int r = 0; r < 4; ++r){ \
      const int ln_ = 4*g16 + r; \
      if (ln_ >= rstart_ && ln_ < rend_){ \
        _Pragma("unroll") \
        for (int nt = 0; nt < 4; ++nt) pacc_[nt] += ev_[r]*ACC[nt][r]; \
        zacc_ += ev_[r]; \
      } \
    } \
    _Pragma("unroll") \
    for (int nt = 0; nt < 4; ++nt) sredp_[g16*64 + nt*16 + jc] = pacc_[nt]; \
    if ((lane & 15) == 0) szl_[g16] = zacc_; \
    __syncthreads(); \
    if (tid < 64){ \
      float s_ = 0.f; \
      for (int g2 = 0; g2 < 16; ++g2) s_ += sredp_[g2*64 + tid]; \
      atomicAdd(&pooled[bseg_*DIM + tid], s_); \
    } \
    if (tid == 64){ \
      float sz2_ = 0.f; \
      for (int g2 = 0; g2 < 16; ++g2) sz2_ += szl_[g2]; \
      atomicAdd(&zbuf[bseg_], sz2_); \
    } \
    __syncthreads(); \
    rstart_ = rend_; \
  } \
} while(0)

// =====================================================================
// MEGA (normal launch + software grid barriers):
//   phase1 lin1 (2 tiles, hpre in regs) -> bar -> phase2 stats ->
//   bar -> phase3 lin2+pool (2 tiles)   -> bar -> phase4 head.
// LDS 53.8KB -> 2 blocks/CU; launch_bounds(256,2) -> VGPR<=256.
// Capacity 2*256=512 >= 391 blocks: all co-resident, barrier safe.
// =====================================================================
__global__ void __launch_bounds__(256, 2) k_mega(
    const float* __restrict__ meanb, const float* __restrict__ x,
    const float* __restrict__ Wl, const float* __restrict__ bl,
    const float* __restrict__ Wr,
    const float* __restrict__ Wres, const float* __restrict__ bres,
    const float* __restrict__ gamma, const float* __restrict__ beta,
    const float* __restrict__ gW1, const float* __restrict__ gb1,
    const float* __restrict__ gW2, const float* __restrict__ gb2,
    const float* __restrict__ Wp1, const float* __restrict__ bp1,
    const float* __restrict__ Wp2, const float* __restrict__ bp2,
    const int* __restrict__ batch,
    float* __restrict__ pstat, float* __restrict__ muinv,
    float* __restrict__ zbuf, float* __restrict__ pooled,
    unsigned* __restrict__ bar, float* __restrict__ outp){
  __shared__ __align__(16) short sA[2][64][72];    // A tiles / scratch
  __shared__ __align__(16) short sB[2][64][136];   // resident weight pair
  __shared__ int sb[64];
  __shared__ unsigned long long runmask;
  __shared__ float psh[DIM];
  __shared__ float redh[4];

  const int tid  = threadIdx.x;
  const int lane = tid & 63, w = tid >> 6;
  const int jc   = lane & 15;
  const int g16  = w*4 + (lane >> 4);
  const int mrow = 16*w + jc;
  const int koff = (lane >> 4) * 8;
  const int r0   = 16*w + (lane >> 4)*4;  // == 4*g16
  const int bx   = blockIdx.x;
  const int baseA = (2*bx) * 64;
  const int baseB = (2*bx + 1) * 64;

  // ================= phase 1: lin1 =================
  float blv[4];
  #pragma unroll
  for (int nt = 0; nt < 4; ++nt) blv[nt] = bl[nt*16 + jc];
  stage_w128(&sB[0][0][0], &sB[1][0][0], Wl, Wr, w, lane);

  f32x4 accA[4] = {};
  f32x4 accB[4] = {};
  LIN1_TILE(baseA, accA);
  LIN1_TILE(baseB, accB);

  float s1v[4] = {0.f,0.f,0.f,0.f}, s2v[4] = {0.f,0.f,0.f,0.f};
  EPI1(baseA, accA);
  EPI1(baseB, accB);
  {
    float* sred = (float*)&sA[0][0][0];
    #pragma unroll
    for (int nt = 0; nt < 4; ++nt){
      float a = s1v[nt], b = s2v[nt];
      a += __shfl_xor(a, 16, 64); a += __shfl_xor(a, 32, 64);
      b += __shfl_xor(b, 16, 64); b += __shfl_xor(b, 32, 64);
      if ((lane >> 4) == 0){
        sred[0*256 + w*64 + nt*16 + jc] = a;
        sred[1*256 + w*64 + nt*16 + jc] = b;
      }
    }
    __syncthreads();
    if (tid < 64){
      float a = sred[tid] + sred[64+tid] + sred[128+tid] + sred[192+tid];
      float b = sred[256+tid] + sred[320+tid] + sred[384+tid] + sred[448+tid];
      gstore(&pstat[(size_t)bx*128 + tid], a);
      gstore(&pstat[(size_t)bx*128 + 64 + tid], b);
    }
  }
  gbar(&bar[0]);

  // ================= phase 2: stats (blocks 0..63) =================
  if (bx < 64){
    float* r1 = (float*)&sA[0][0][0];
    float* r2 = r1 + 256;
    float s1 = 0.f, s2 = 0.f;
    for (int c = tid; c < NBLK; c += 256){
      s1 += gload(&pstat[(size_t)c*128 + bx]);
      s2 += gload(&pstat[(size_t)c*128 + 64 + bx]);
    }
    r1[tid] = s1; r2[tid] = s2;
    __syncthreads();
    for (int st = 128; st > 0; st >>= 1){
      if (tid < st){ r1[tid] += r1[tid+st]; r2[tid] += r2[tid+st]; }
      __syncthreads();
    }
    if (tid == 0){
      float mu = r1[0] / (float)N_NODES;
      float var = r2[0] / (float)N_NODES - mu*mu;
      gstore(&muinv[bx], mu);
      gstore(&muinv[DIM+bx], 1.0f / sqrtf(var + EPSV));
    }
  }
  gbar(&bar[1]);

  // ================= phase 3: lin2 + pooling =================
  float muv[4], invv[4], gav[4], bev[4], brv[4], g1v[4], w2v[4];
  #pragma unroll
  for (int nt = 0; nt < 4; ++nt){
    const int col = nt*16 + jc;
    muv[nt] = gload(&muinv[col]);  invv[nt] = gload(&muinv[DIM+col]);
    gav[nt] = gamma[col];   bev[nt] = beta[col];
    brv[nt] = bres[col];    g1v[nt] = gb1[col];
    w2v[nt] = gW2[col];
  }
  const float gb2v = gb2[0];
  stage_w128(&sB[0][0][0], &sB[1][0][0], Wres, gW1, w, lane);

  LIN2_TILE(baseA, accA);
  LIN2_TILE(baseB, accB);
  gbar(&bar[2]);

  // ================= phase 4: head (blocks 0..127) =================
  if (bx < BATCHES){
    const int b = bx;
    const int t = tid;
    if (t < DIM){
      float zz = fmaxf(gload(&zbuf[b]), 1e-16f);
      psh[t] = gload(&pooled[b*DIM + t]) / zz;
    }
    __syncthreads();
    if (t < HID){
      float a = bp1[t];
      #pragma unroll
      for (int d2 = 0; d2 < DIM; ++d2) a = fmaf(psh[d2], Wp1[d2*HID + t], a);
      a = fmaxf(a, 0.f);
      float o0 = a * Wp2[t*NCLS+0];
      float o1 = a * Wp2[t*NCLS+1];
      #pragma unroll
      for (int o = 32; o > 0; o >>= 1){
        o0 += __shfl_down(o0, o, 64); o1 += __shfl_down(o1, o, 64);
      }
      int hw = t >> 6;
      if ((t & 63) == 0){ redh[hw*2+0] = o0; redh[hw*2+1] = o1; }
    }
    __syncthreads();
    if (t == 0){
      outp[b*NCLS+0] = redh[0]+redh[2]+bp2[0];
      outp[b*NCLS+1] = redh[1]+redh[3]+bp2[1];
    }
  }
}

extern "C" void kernel_launch(void* const* d_in, const int* in_sizes, int n_in,
                              void* d_out, int out_size, void* d_ws, size_t ws_size,
                              hipStream_t stream){
  const float* x     = (const float*)d_in[0];
  const int*   ei    = (const int*)d_in[1];
  const int*   batch = (const int*)d_in[2];
  const float* Wl    = (const float*)d_in[3];
  const float* bl    = (const float*)d_in[4];
  const float* Wr    = (const float*)d_in[5];
  const float* Wres  = (const float*)d_in[6];
  const float* bres  = (const float*)d_in[7];
  const float* gamma = (const float*)d_in[8];
  const float* beta  = (const float*)d_in[9];
  const float* gW1   = (const float*)d_in[10];
  const float* gb1   = (const float*)d_in[11];
  const float* gW2   = (const float*)d_in[12];
  const float* gb2   = (const float*)d_in[13];
  const float* Wp1   = (const float*)d_in[14];
  const float* bp1   = (const float*)d_in[15];
  const float* Wp2   = (const float*)d_in[16];
  const float* bp2   = (const float*)d_in[17];
  float* outp = (float*)d_out;

  // ---- workspace carve (zero-init region first, contiguous) ----
  int*      cnt    = (int*)d_ws;                        // N        (zeroed)
  float*    zbuf   = (float*)(cnt + N_NODES);           // B        (zeroed)
  float*    pooled = zbuf + BATCHES;                    // B*D      (zeroed)
  unsigned* bar    = (unsigned*)(pooled + (size_t)BATCHES*DIM); // 8 (zeroed)
  float*    pstat  = (float*)(bar + 8);                 // NBLK*128
  float*    muinv  = pstat + (size_t)NBLK*128;          // 128
  float*    meanb  = muinv + 2*DIM;                     // N*D
  unsigned short* csr = (unsigned short*)(meanb + (size_t)N_NODES*DIM); // N*MAXD u16

  const size_t zcount = (size_t)N_NODES + BATCHES + (size_t)BATCHES*DIM + 8;
  hipMemsetAsync(d_ws, 0, zcount*sizeof(int), stream);

  k_scatter<<<NPART*NCHK_E, 256, 0, stream>>>(ei, cnt, csr);
  k_mean   <<<N_NODES/4, 256, 0, stream>>>(x, csr, cnt, meanb);
  k_mega   <<<NBLK, 256, 0, stream>>>(meanb, x, Wl, bl, Wr, Wres, bres,
                                      gamma, beta, gW1, gb1, gW2, gb2,
                                      Wp1, bp1, Wp2, bp2, batch,
                                      pstat, muinv, zbuf, pooled, bar, outp);
}